// Round 1
// baseline (429.276 us; speedup 1.0000x reference)
//
#include <hip/hip_runtime.h>
#include <hip/hip_bf16.h>

// MultiAttnMatch — cross attention
// B=16, L1=1024, L2=1024, DIN=1024, H=16, DK=DV=64
#define BATCH 16
#define L1D 1024
#define L2D 1024
#define DIN 1024
#define NH 16
#define HD 1024   // NH*DK = NH*DV (output row stride)
#define OHD 3072  // fused QKV row stride

typedef __attribute__((ext_vector_type(4))) float floatx4;
typedef __attribute__((ext_vector_type(8))) short shortx8;
typedef __attribute__((ext_vector_type(8))) unsigned short ushortx8;

#if __has_builtin(__builtin_amdgcn_exp2f)
#define EXP2(x) __builtin_amdgcn_exp2f(x)
#else
#define EXP2(x) exp2f(x)
#endif

static __device__ __forceinline__ unsigned short f2bf(float f) {  // RNE
    union { float f; unsigned u; } v; v.f = f;
    unsigned r = v.u + 0x7fff + ((v.u >> 16) & 1);
    return (unsigned short)(r >> 16);
}
static __device__ __forceinline__ unsigned short f2bf_fast(float f) {  // round-half-up
    union { float f; unsigned u; } v; v.f = f;
    return (unsigned short)((v.u + 0x8000u) >> 16);
}

#define GLOBAL_AS __attribute__((address_space(1)))
#define LDS_AS __attribute__((address_space(3)))
static __device__ __forceinline__ void gl2lds16(const unsigned short* g, unsigned short* l) {
    __builtin_amdgcn_global_load_lds((const GLOBAL_AS unsigned int*)g,
                                     (LDS_AS unsigned int*)l, 16, 0, 0);
}

// ---------------------------------------------------------------------------
// prep: cvt x -> xb, cvt y -> yb (fp32->bf16, 8/thread), mask -> float bias
// ---------------------------------------------------------------------------
#define NCVT 8192  // T/2048 blocks per tensor
__global__ void prep_kernel(const float* __restrict__ x, const float* __restrict__ y,
                            unsigned short* __restrict__ xb, unsigned short* __restrict__ yb,
                            const int* __restrict__ ym, float* __restrict__ biasf) {
    int bid = blockIdx.x;
    if (bid < 2 * NCVT) {
        const float* in = bid < NCVT ? x : y;
        unsigned short* o = bid < NCVT ? xb : yb;
        int bb = bid < NCVT ? bid : bid - NCVT;
        size_t i = ((size_t)bb * 256 + threadIdx.x) * 8;
        float4 a = *(const float4*)(in + i);
        float4 b = *(const float4*)(in + i + 4);
        ushortx8 v;
        v[0] = f2bf(a.x); v[1] = f2bf(a.y); v[2] = f2bf(a.z); v[3] = f2bf(a.w);
        v[4] = f2bf(b.x); v[5] = f2bf(b.y); v[6] = f2bf(b.z); v[7] = f2bf(b.w);
        *(ushortx8*)(o + i) = v;
    } else {
        int i = (bid - 2 * NCVT) * 256 + threadIdx.x;
        biasf[i] = ym[i] ? -INFINITY : 0.0f;
    }
}

// ---------------------------------------------------------------------------
// W [DIN][HD] fp32 -> Wt [3*HD][DIN] bf16 (transpose + convert), z = section
// ---------------------------------------------------------------------------
__global__ void wt_kernel(const float* __restrict__ Wq, const float* __restrict__ Wk,
                          const float* __restrict__ Wv, unsigned short* __restrict__ Wt) {
    __shared__ float tile[32][33];
    const float* W = blockIdx.z == 0 ? Wq : (blockIdx.z == 1 ? Wk : Wv);
    unsigned short* dst = Wt + (size_t)blockIdx.z * HD * DIN;
    int bx = blockIdx.x, by = blockIdx.y;
    int tx = threadIdx.x, ty = threadIdx.y;
    for (int i = 0; i < 4; i++)
        tile[ty + i * 8][tx] = W[(size_t)(by * 32 + ty + i * 8) * HD + bx * 32 + tx];
    __syncthreads();
    for (int i = 0; i < 4; i++)
        dst[(size_t)(bx * 32 + ty + i * 8) * DIN + by * 32 + tx] = f2bf(tile[tx][ty + i * 8]);
}

// ---------------------------------------------------------------------------
// Fused QKV GEMM: Out[m][3072] = bf16((A_sec @ W_sec + bias_sec) * scale_sec)
//   A: xb (sec 0) / yb (sec 1,2), [16384][1024] bf16 k-contig
//   Wt: [3072][1024] bf16 n-major k-contig
// Tile 128x128, BK=32, global_load_lds + XOR chunk swizzle (2-way banks).
// ---------------------------------------------------------------------------
__global__ __launch_bounds__(256, 2) void gemm_kernel(
    const unsigned short* __restrict__ xb, const unsigned short* __restrict__ yb,
    const unsigned short* __restrict__ Wt,
    const float* __restrict__ bq, const float* __restrict__ bk, const float* __restrict__ bvp,
    unsigned short* __restrict__ Out, float qscale)
{
    __shared__ unsigned short As[128 * 32];
    __shared__ unsigned short Bs[128 * 32];
    const int n0 = blockIdx.x * 128;       // 0..3071
    const int m0 = blockIdx.y * 128;
    const int sec = n0 >> 10;
    const unsigned short* A = (sec == 0) ? xb : yb;
    const float* bias = (sec == 0) ? bq : (sec == 1 ? bk : bvp);
    const float scale = (sec == 0) ? qscale : 1.0f;

    const int tid = threadIdx.x;
    const int wid = tid >> 6, lane = tid & 63;
    const int c = lane & 15, qd = lane >> 4;
    const int wm = (wid >> 1) * 64, wn = (wid & 1) * 64;

    // staging indices (loop-invariant): 16B chunk f16 -> row, swizzled col
    int f16a = tid, f16b = 256 + tid;
    int rowA = f16a >> 2, scA = ((f16a & 3) ^ ((rowA >> 1) & 3)) * 8;
    int rowB = f16b >> 2, scB = ((f16b & 3) ^ ((rowB >> 1) & 3)) * 8;
    // fragment read swizzle (chunk = qd, xor (row>>1)&3 = (c>>1)&3)
    const int swz = (qd ^ ((c >> 1) & 3)) * 8;

    floatx4 acc[4][4] = {};

    for (int k0 = 0; k0 < DIN; k0 += 32) {
        gl2lds16(A  + (size_t)(m0 + rowA) * DIN + k0 + scA, &As[f16a * 8]);
        gl2lds16(Wt + (size_t)(n0 + rowA) * DIN + k0 + scA, &Bs[f16a * 8]);
        gl2lds16(A  + (size_t)(m0 + rowB) * DIN + k0 + scB, &As[f16b * 8]);
        gl2lds16(Wt + (size_t)(n0 + rowB) * DIN + k0 + scB, &Bs[f16b * 8]);
        __syncthreads();

        shortx8 a[4], b[4];
        for (int mt = 0; mt < 4; mt++)
            a[mt] = *(shortx8*)(&As[(wm + mt * 16 + c) * 32 + swz]);
        for (int nt = 0; nt < 4; nt++)
            b[nt] = *(shortx8*)(&Bs[(wn + nt * 16 + c) * 32 + swz]);
        for (int mt = 0; mt < 4; mt++)
            for (int nt = 0; nt < 4; nt++)
                acc[mt][nt] = __builtin_amdgcn_mfma_f32_16x16x32_bf16(
                    a[mt], b[nt], acc[mt][nt], 0, 0, 0);
        __syncthreads();
    }

    for (int nt = 0; nt < 4; nt++) {
        int gn = n0 + wn + nt * 16 + c;
        float bv = bias[gn & 1023];
        for (int mt = 0; mt < 4; mt++)
            for (int r = 0; r < 4; r++) {
                int gm = m0 + wm + mt * 16 + qd * 4 + r;
                Out[(size_t)gm * OHD + gn] = f2bf((acc[mt][nt][r] + bv) * scale);
            }
    }
}

// ---------------------------------------------------------------------------
// V (Obuf cols 2048..3071, stride 3072) -> Vt [(b*16+h)*64+dv][l2] bf16
// ---------------------------------------------------------------------------
__global__ void vt_kernel(const unsigned short* __restrict__ V,
                          unsigned short* __restrict__ Vt) {
    __shared__ unsigned short t[64][72];
    const int l20 = blockIdx.x * 64;
    const int bh  = blockIdx.y;
    const int b = bh >> 4, h = bh & 15;
    const int tid = threadIdx.x;
    for (int i = 0; i < 2; i++) {
        int idx = i * 256 + tid;
        int row = idx >> 3, col = (idx & 7) * 8;
        *(ushortx8*)(&t[row][col]) =
            *(const ushortx8*)(V + (size_t)(b * L2D + l20 + row) * OHD + h * 64 + col);
    }
    __syncthreads();
    for (int i = 0; i < 2; i++) {
        int idx = i * 256 + tid;
        int dv = idx >> 3, col = (idx & 7) * 8;
        ushortx8 v;
        for (int j = 0; j < 8; j++) v[j] = t[col + j][dv];
        *(ushortx8*)(Vt + (size_t)(bh * 64 + dv) * L2D + l20 + col) = v;
    }
}

// ---------------------------------------------------------------------------
// Attention: no-max exp2 softmax, Q-block 128, KV tiles 64.
// K/V staged via global_load_lds with XOR chunk swizzle (2-way banks).
// XCD-aware block remap so the 8 q-blocks of one (b,h) share one L2.
// ---------------------------------------------------------------------------
__global__ __launch_bounds__(256, 4) void attn_kernel(
    const unsigned short* __restrict__ QK,   // Obuf: Q = col 0, K = col 1024
    const unsigned short* __restrict__ Vt, const float* __restrict__ biasf,
    float* __restrict__ out)
{
    __shared__ unsigned short Ks[64 * 64];
    __shared__ unsigned short Vs[64 * 64];
    __shared__ unsigned short Ps[4][32 * 72];

    // remap: same-XCD blocks (flat%8) share bh
    int f = blockIdx.y * gridDim.x + blockIdx.x;   // 0..2047
    int bh = (f & 7) * 32 + (f >> 6);
    int q0 = ((f >> 3) & 7) * 128;
    const int b = bh >> 4, h = bh & 15;
    const int tid = threadIdx.x, wid = tid >> 6, lane = tid & 63;
    const int c = lane & 15, qd = lane >> 4;

    // Q A-fragments (Q pre-scaled by 0.125*log2e in GEMM epilogue)
    shortx8 qf[2][2];
    for (int mt2 = 0; mt2 < 2; mt2++)
        for (int kt = 0; kt < 2; kt++)
            qf[mt2][kt] = *(const shortx8*)(QK +
                (size_t)(b * L1D + q0 + wid * 32 + mt2 * 16 + c) * OHD + h * 64 + kt * 32 + qd * 8);

    floatx4 o[2][4] = {};
    float psum[2][4] = {};

    const unsigned short* Kbase = QK + HD + (size_t)b * L2D * OHD + h * 64;
    const unsigned short* Vbase = Vt + (size_t)bh * 64 * L2D;
    const float* bb = biasf + b * L2D;

    // staging indices (loop-invariant)
    int idxa = tid, idxb = 256 + tid;
    int rowa = idxa >> 3, sca = ((idxa & 7) ^ (rowa & 7)) * 8;
    int rowb = idxb >> 3, scb = ((idxb & 7) ^ (rowb & 7)) * 8;
    const int swz8 = c & 7;  // frag-read xor

    for (int kv0 = 0; kv0 < L2D; kv0 += 64) {
        gl2lds16(Kbase + (size_t)(kv0 + rowa) * OHD + sca, &Ks[idxa * 8]);
        gl2lds16(Vbase + (size_t)rowa * L2D + kv0 + sca, &Vs[idxa * 8]);
        gl2lds16(Kbase + (size_t)(kv0 + rowb) * OHD + scb, &Ks[idxb * 8]);
        gl2lds16(Vbase + (size_t)rowb * L2D + kv0 + scb, &Vs[idxb * 8]);
        __syncthreads();

        float bv[4];
        for (int nt = 0; nt < 4; nt++) bv[nt] = bb[kv0 + nt * 16 + c];

        for (int mt2 = 0; mt2 < 2; mt2++) {
            for (int nt = 0; nt < 4; nt++) {
                floatx4 z = {};
                for (int kt = 0; kt < 2; kt++) {
                    shortx8 kf = *(shortx8*)(&Ks[(nt * 16 + c) * 64 + ((kt * 4 + qd) ^ swz8) * 8]);
                    z = __builtin_amdgcn_mfma_f32_16x16x32_bf16(qf[mt2][kt], kf, z, 0, 0, 0);
                }
                for (int r = 0; r < 4; r++) {
                    float p = EXP2(z[r] + bv[nt]);
                    psum[mt2][r] += p;
                    Ps[wid][(mt2 * 16 + qd * 4 + r) * 72 + nt * 16 + c] = f2bf_fast(p);
                }
            }
        }
        for (int mt2 = 0; mt2 < 2; mt2++) {
            shortx8 pf[2];
            for (int kt = 0; kt < 2; kt++)
                pf[kt] = *(shortx8*)(&Ps[wid][(mt2 * 16 + c) * 72 + kt * 32 + qd * 8]);
            for (int nt = 0; nt < 4; nt++)
                for (int kt = 0; kt < 2; kt++) {
                    shortx8 vf = *(shortx8*)(&Vs[(nt * 16 + c) * 64 + ((kt * 4 + qd) ^ swz8) * 8]);
                    o[mt2][nt] = __builtin_amdgcn_mfma_f32_16x16x32_bf16(pf[kt], vf, o[mt2][nt], 0, 0, 0);
                }
        }
        __syncthreads();
    }

    for (int mt2 = 0; mt2 < 2; mt2++)
        for (int r = 0; r < 4; r++) {
            float l = psum[mt2][r];
            for (int off = 1; off < 16; off <<= 1)
                l += __shfl_xor(l, off, 64);
            float inv = 1.0f / l;
            size_t rowbase = ((size_t)b * L1D + q0 + wid * 32 + mt2 * 16 + qd * 4 + r) * HD + h * 64;
            for (int nt = 0; nt < 4; nt++)
                out[rowbase + nt * 16 + c] = o[mt2][nt][r] * inv;
        }
}

// ---------------------------------------------------------------------------
extern "C" void kernel_launch(void* const* d_in, const int* in_sizes, int n_in,
                              void* d_out, int out_size, void* d_ws, size_t ws_size,
                              hipStream_t stream) {
    const float* x  = (const float*)d_in[0];
    const float* y  = (const float*)d_in[1];
    const int*  ym  = (const int*)d_in[2];
    const float* Wq = (const float*)d_in[3];
    const float* bq = (const float*)d_in[4];
    const float* Wk = (const float*)d_in[5];
    const float* bk = (const float*)d_in[6];
    const float* Wv = (const float*)d_in[7];
    const float* bv = (const float*)d_in[8];
    float* outp = (float*)d_out;

    const size_t M = (size_t)BATCH * L1D;      // 16384
    const size_t T = M * HD;                   // 16.78M
    unsigned short* Obuf = (unsigned short*)d_ws;     // M*3072 (QKV fused)
    unsigned short* xb   = Obuf + M * OHD;            // T ; reused as Vt after gemm
    unsigned short* yb   = xb + T;                    // T
    unsigned short* Wt   = yb + T;                    // 3072*1024
    float* biasf         = (float*)(Wt + (size_t)OHD * DIN);
    // total ~174 MB

    const float QSCALE = 0.125f * 1.44269504088896340736f;  // 1/sqrt(64)*log2(e)

    prep_kernel<<<2 * NCVT + (BATCH * L2D) / 256, 256, 0, stream>>>(x, y, xb, yb, ym, biasf);
    wt_kernel<<<dim3(HD / 32, DIN / 32, 3), dim3(32, 8), 0, stream>>>(Wq, Wk, Wv, Wt);
    gemm_kernel<<<dim3(OHD / 128, M / 128), 256, 0, stream>>>(xb, yb, Wt, bq, bk, bv, Obuf, QSCALE);
    vt_kernel<<<dim3(L2D / 64, BATCH * NH), 256, 0, stream>>>(Obuf + 2 * HD, xb);
    attn_kernel<<<dim3(L1D / 128, BATCH * NH), 256, 0, stream>>>(Obuf, xb, biasf, outp);
}

// Round 3
// 412.915 us; speedup vs baseline: 1.0396x; 1.0396x over previous
//
#include <hip/hip_runtime.h>
#include <hip/hip_bf16.h>

// MultiAttnMatch — cross attention
// B=16, L1=1024, L2=1024, DIN=1024, H=16, DK=DV=64
#define BATCH 16
#define L1D 1024
#define L2D 1024
#define DIN 1024
#define NH 16
#define HD 1024   // NH*DK = NH*DV (output row stride)
#define OHD 3072  // fused QKV row stride

typedef __attribute__((ext_vector_type(4))) float floatx4;
typedef __attribute__((ext_vector_type(8))) short shortx8;
typedef __attribute__((ext_vector_type(8))) unsigned short ushortx8;

#if __has_builtin(__builtin_amdgcn_exp2f)
#define EXP2(x) __builtin_amdgcn_exp2f(x)
#else
#define EXP2(x) exp2f(x)
#endif

static __device__ __forceinline__ unsigned short f2bf(float f) {  // RNE
    union { float f; unsigned u; } v; v.f = f;
    unsigned r = v.u + 0x7fff + ((v.u >> 16) & 1);
    return (unsigned short)(r >> 16);
}
static __device__ __forceinline__ unsigned short f2bf_fast(float f) {  // round-half-up
    union { float f; unsigned u; } v; v.f = f;
    return (unsigned short)((v.u + 0x8000u) >> 16);
}

#define GLOBAL_AS __attribute__((address_space(1)))
#define LDS_AS __attribute__((address_space(3)))
static __device__ __forceinline__ void gl2lds16(const unsigned short* g, unsigned short* l) {
    __builtin_amdgcn_global_load_lds((const GLOBAL_AS unsigned int*)g,
                                     (LDS_AS unsigned int*)l, 16, 0, 0);
}

// ---------------------------------------------------------------------------
// prep: cvt x -> xb, cvt y -> yb (fp32->bf16, 8/thread), mask -> float bias
// ---------------------------------------------------------------------------
#define NCVT 8192  // T/2048 blocks per tensor
__global__ void prep_kernel(const float* __restrict__ x, const float* __restrict__ y,
                            unsigned short* __restrict__ xb, unsigned short* __restrict__ yb,
                            const int* __restrict__ ym, float* __restrict__ biasf) {
    int bid = blockIdx.x;
    if (bid < 2 * NCVT) {
        const float* in = bid < NCVT ? x : y;
        unsigned short* o = bid < NCVT ? xb : yb;
        int bb = bid < NCVT ? bid : bid - NCVT;
        size_t i = ((size_t)bb * 256 + threadIdx.x) * 8;
        float4 a = *(const float4*)(in + i);
        float4 b = *(const float4*)(in + i + 4);
        ushortx8 v;
        v[0] = f2bf(a.x); v[1] = f2bf(a.y); v[2] = f2bf(a.z); v[3] = f2bf(a.w);
        v[4] = f2bf(b.x); v[5] = f2bf(b.y); v[6] = f2bf(b.z); v[7] = f2bf(b.w);
        *(ushortx8*)(o + i) = v;
    } else {
        int i = (bid - 2 * NCVT) * 256 + threadIdx.x;
        biasf[i] = ym[i] ? -INFINITY : 0.0f;
    }
}

// ---------------------------------------------------------------------------
// W [DIN][HD] fp32 -> Wt [3*HD][DIN] bf16 (transpose + convert), z = section
// ---------------------------------------------------------------------------
__global__ void wt_kernel(const float* __restrict__ Wq, const float* __restrict__ Wk,
                          const float* __restrict__ Wv, unsigned short* __restrict__ Wt) {
    __shared__ float tile[32][33];
    const float* W = blockIdx.z == 0 ? Wq : (blockIdx.z == 1 ? Wk : Wv);
    unsigned short* dst = Wt + (size_t)blockIdx.z * HD * DIN;
    int bx = blockIdx.x, by = blockIdx.y;
    int tx = threadIdx.x, ty = threadIdx.y;
    for (int i = 0; i < 4; i++)
        tile[ty + i * 8][tx] = W[(size_t)(by * 32 + ty + i * 8) * HD + bx * 32 + tx];
    __syncthreads();
    for (int i = 0; i < 4; i++)
        dst[(size_t)(bx * 32 + ty + i * 8) * DIN + by * 32 + tx] = f2bf(tile[tx][ty + i * 8]);
}

// ---------------------------------------------------------------------------
// Fused QKV GEMM — 256x256 tile, BK=64, 8 waves (2Mx4N), 8-phase schedule.
// Counted vmcnt(4) at phases 4/8 (never 0 mid-loop), raw s_barrier (no
// __syncthreads vmcnt drain), chunk-XOR swizzled LDS (src-preswizzled,
// linear global_load_lds dest), setprio(1) around MFMA clusters.
//   A: xb (sec 0) / yb (sec 1,2), [16384][1024] bf16 k-contig
//   Wt: [3072][1024] bf16 n-major k-contig
//   Out[m][3072] = bf16((A_sec @ W_sec^T + bias_sec) * scale_sec)
// ---------------------------------------------------------------------------
__global__ __launch_bounds__(512, 2) void gemm_kernel(
    const unsigned short* __restrict__ xb, const unsigned short* __restrict__ yb,
    const unsigned short* __restrict__ Wt,
    const float* __restrict__ bq, const float* __restrict__ bk, const float* __restrict__ bvp,
    unsigned short* __restrict__ Out, float qscale)
{
    __shared__ unsigned short As[2][256 * 64];   // 64 KB (double-buffered K-tiles)
    __shared__ unsigned short Bs[2][256 * 64];   // 64 KB

    // XCD-aware remap: nwg = 12*64 = 768 = 96/XCD (bijective, 768%8==0)
    int f = blockIdx.y * gridDim.x + blockIdx.x;
    int swz = (f & 7) * 96 + (f >> 3);
    const int n0 = (swz % 12) * 256;
    const int m0 = (swz / 12) * 256;
    const int sec = n0 >> 10;
    const unsigned short* Aptr = (sec == 0) ? xb : yb;
    const float* bias = (sec == 0) ? bq : (sec == 1 ? bk : bvp);
    const float scale = (sec == 0) ? qscale : 1.0f;

    const int tid = threadIdx.x;
    const int wid = tid >> 6, lane = tid & 63;
    const int c = lane & 15, qd = lane >> 4;
    const int cswz = c & 7;                 // fragment-read chunk XOR
    const int R0 = (wid >> 2) * 128;        // wave M offset (2 wave-rows)
    const int C0 = (wid & 3) * 64;          // wave N offset (4 wave-cols)

    // staging thread map: one gl2lds16 covers 64 rows x 64 cols (8KB/512thr)
    const int srow = tid >> 3;              // 0..63
    const int sphys = tid & 7;              // phys 16B chunk in row
    const int scol = (sphys ^ (srow & 7)) * 8;  // pre-swizzled global col

    floatx4 acc[8][4] = {};
    shortx8 a[4][2];            // current A half (4 m-frags x 2 k-chunks)
    shortx8 b0[2][2], b1[2][2]; // both B halves of current K-tile

    auto dsrdA = [&](int mq, const unsigned short* buf) {
#pragma unroll
        for (int i = 0; i < 4; i++)
#pragma unroll
            for (int kk = 0; kk < 2; kk++)
                a[i][kk] = *(const shortx8*)&buf[(R0 + mq * 64 + i * 16 + c) * 64 +
                                                 (((kk * 4 + qd) ^ cswz) * 8)];
    };
    auto dsrdB = [&](shortx8 (&bt)[2][2], int nq, const unsigned short* buf) {
#pragma unroll
        for (int j = 0; j < 2; j++)
#pragma unroll
            for (int kk = 0; kk < 2; kk++)
                bt[j][kk] = *(const shortx8*)&buf[(C0 + (nq * 2 + j) * 16 + c) * 64 +
                                                  (((kk * 4 + qd) ^ cswz) * 8)];
    };
    auto mfmaQ = [&](int mq, int nq, shortx8 (&bt)[2][2]) {
        __builtin_amdgcn_s_setprio(1);
#pragma unroll
        for (int kk = 0; kk < 2; kk++)
#pragma unroll
            for (int i = 0; i < 4; i++)
#pragma unroll
                for (int j = 0; j < 2; j++)
                    acc[mq * 4 + i][nq * 2 + j] = __builtin_amdgcn_mfma_f32_16x16x32_bf16(
                        a[i][kk], bt[j][kk], acc[mq * 4 + i][nq * 2 + j], 0, 0, 0);
        __builtin_amdgcn_s_setprio(0);
    };
    auto stageA = [&](unsigned short* dst, int h, int kt) {  // one half-tile (2 loads)
        const unsigned short* g = Aptr + (size_t)(m0 + h * 128 + srow) * DIN + kt * 64 + scol;
        unsigned short* l = dst + (h * 128 + srow) * 64 + sphys * 8;
        gl2lds16(g, l);
        gl2lds16(g + (size_t)64 * DIN, l + 64 * 64);
    };
    auto stageB = [&](unsigned short* dst, int h, int kt) {
        const unsigned short* g = Wt + (size_t)(n0 + h * 128 + srow) * DIN + kt * 64 + scol;
        unsigned short* l = dst + (h * 128 + srow) * 64 + sphys * 8;
        gl2lds16(g, l);
        gl2lds16(g + (size_t)64 * DIN, l + 64 * 64);
    };

    // bias preload FIRST + drain, so no stray VMEM pollutes vmcnt counting
    float biasv[4];
#pragma unroll
    for (int nf = 0; nf < 4; nf++)
        biasv[nf] = bias[((n0 & 1023) + C0 + nf * 16 + c) & 1023];
    asm volatile("s_waitcnt vmcnt(0)" ::: "memory");

    // prologue: tile0 full (buf0, 8 loads) + tile1 B (buf1, 4 loads)
    stageB(Bs[0], 0, 0); stageB(Bs[0], 1, 0);
    stageA(As[0], 0, 0); stageA(As[0], 1, 0);
    stageB(Bs[1], 0, 1); stageB(Bs[1], 1, 1);
    asm volatile("s_waitcnt vmcnt(4)" ::: "memory");   // tile0 arrived
    __builtin_amdgcn_s_barrier();

    // 16 K-tiles, 2 per iteration (even->buf0, odd->buf1)
    for (int it = 0; it < 8; ++it) {
        const int kt1 = 2 * it + 1;       // odd tile read this iter (buf1)
        const int ktp = 2 * it + 2;       // prefetched even tile (buf0)
        const bool pf = (it < 7);

        // P1: tile2i (buf0), quadrant (mh0,nh0); stage tile(2i+1) A half0
        dsrdA(0, As[0]); dsrdB(b0, 0, Bs[0]);
        stageA(As[1], 0, kt1);
        __builtin_amdgcn_s_barrier();
        asm volatile("s_waitcnt lgkmcnt(0)" ::: "memory");
        mfmaQ(0, 0, b0);
        __builtin_amdgcn_s_barrier();

        // P2: (mh0,nh1); stage tile(2i+1) A half1
        dsrdB(b1, 1, Bs[0]);
        stageA(As[1], 1, kt1);
        __builtin_amdgcn_s_barrier();
        asm volatile("s_waitcnt lgkmcnt(0)" ::: "memory");
        mfmaQ(0, 1, b1);
        __builtin_amdgcn_s_barrier();

        // P3: (mh1,nh1); buf0-B free since end P2 -> stage tile(2i+2) B half0
        dsrdA(1, As[0]);
        if (pf) stageB(Bs[0], 0, ktp);
        __builtin_amdgcn_s_barrier();
        asm volatile("s_waitcnt lgkmcnt(0)" ::: "memory");
        mfmaQ(1, 1, b1);
        __builtin_amdgcn_s_barrier();

        // P4: (mh1,nh0); stage tile(2i+2) B half1; wait: tile(2i+1) complete
        if (pf) stageB(Bs[0], 1, ktp);
        __builtin_amdgcn_s_barrier();
        mfmaQ(1, 0, b0);
        if (pf) asm volatile("s_waitcnt vmcnt(4)" ::: "memory");
        else    asm volatile("s_waitcnt vmcnt(0)" ::: "memory");
        __builtin_amdgcn_s_barrier();

        // P5: tile2i+1 (buf1), (mh0,nh0); buf0-A free since P3 -> stage A half0
        dsrdA(0, As[1]); dsrdB(b0, 0, Bs[1]);
        if (pf) stageA(As[0], 0, ktp);
        __builtin_amdgcn_s_barrier();
        asm volatile("s_waitcnt lgkmcnt(0)" ::: "memory");
        mfmaQ(0, 0, b0);
        __builtin_amdgcn_s_barrier();

        // P6: (mh0,nh1); stage tile(2i+2) A half1
        dsrdB(b1, 1, Bs[1]);
        if (pf) stageA(As[0], 1, ktp);
        __builtin_amdgcn_s_barrier();
        asm volatile("s_waitcnt lgkmcnt(0)" ::: "memory");
        mfmaQ(0, 1, b1);
        __builtin_amdgcn_s_barrier();

        // P7: (mh1,nh1); buf1-B free since P6 -> stage tile(2i+3) B half0
        dsrdA(1, As[1]);
        if (pf) stageB(Bs[1], 0, ktp + 1);
        __builtin_amdgcn_s_barrier();
        asm volatile("s_waitcnt lgkmcnt(0)" ::: "memory");
        mfmaQ(1, 1, b1);
        __builtin_amdgcn_s_barrier();

        // P8: (mh1,nh0); stage tile(2i+3) B half1; wait: tile(2i+2) complete
        if (pf) stageB(Bs[1], 1, ktp + 1);
        __builtin_amdgcn_s_barrier();
        mfmaQ(1, 0, b0);
        if (pf) asm volatile("s_waitcnt vmcnt(4)" ::: "memory");
        __builtin_amdgcn_s_barrier();
    }

    // epilogue: bias + scale + bf16 convert, scalar stores (no LDS deps)
#pragma unroll
    for (int nf = 0; nf < 4; nf++) {
        const int gn = n0 + C0 + nf * 16 + c;
        const float bvv = biasv[nf];
#pragma unroll
        for (int mf = 0; mf < 8; mf++)
#pragma unroll
            for (int r = 0; r < 4; r++) {
                const int gm = m0 + R0 + mf * 16 + qd * 4 + r;
                Out[(size_t)gm * OHD + gn] = f2bf((acc[mf][nf][r] + bvv) * scale);
            }
    }
}

// ---------------------------------------------------------------------------
// V (Obuf cols 2048..3071, stride 3072) -> Vt [(b*16+h)*64+dv][l2] bf16
// ---------------------------------------------------------------------------
__global__ void vt_kernel(const unsigned short* __restrict__ V,
                          unsigned short* __restrict__ Vt) {
    __shared__ unsigned short t[64][72];
    const int l20 = blockIdx.x * 64;
    const int bh  = blockIdx.y;
    const int b = bh >> 4, h = bh & 15;
    const int tid = threadIdx.x;
    for (int i = 0; i < 2; i++) {
        int idx = i * 256 + tid;
        int row = idx >> 3, col = (idx & 7) * 8;
        *(ushortx8*)(&t[row][col]) =
            *(const ushortx8*)(V + (size_t)(b * L2D + l20 + row) * OHD + h * 64 + col);
    }
    __syncthreads();
    for (int i = 0; i < 2; i++) {
        int idx = i * 256 + tid;
        int dv = idx >> 3, col = (idx & 7) * 8;
        ushortx8 v;
        for (int j = 0; j < 8; j++) v[j] = t[col + j][dv];
        *(ushortx8*)(Vt + (size_t)(bh * 64 + dv) * L2D + l20 + col) = v;
    }
}

// ---------------------------------------------------------------------------
// Attention: no-max exp2 softmax, Q-block 128, KV tiles 64.
// K/V staged via global_load_lds with XOR chunk swizzle (2-way banks).
// XCD-aware block remap so the 8 q-blocks of one (b,h) share one L2.
// ---------------------------------------------------------------------------
__global__ __launch_bounds__(256, 4) void attn_kernel(
    const unsigned short* __restrict__ QK,   // Obuf: Q = col 0, K = col 1024
    const unsigned short* __restrict__ Vt, const float* __restrict__ biasf,
    float* __restrict__ out)
{
    __shared__ unsigned short Ks[64 * 64];
    __shared__ unsigned short Vs[64 * 64];
    __shared__ unsigned short Ps[4][32 * 72];

    // remap: same-XCD blocks (flat%8) share bh
    int f = blockIdx.y * gridDim.x + blockIdx.x;   // 0..2047
    int bh = (f & 7) * 32 + (f >> 6);
    int q0 = ((f >> 3) & 7) * 128;
    const int b = bh >> 4, h = bh & 15;
    const int tid = threadIdx.x, wid = tid >> 6, lane = tid & 63;
    const int c = lane & 15, qd = lane >> 4;

    // Q A-fragments (Q pre-scaled by 0.125*log2e in GEMM epilogue)
    shortx8 qf[2][2];
    for (int mt2 = 0; mt2 < 2; mt2++)
        for (int kt = 0; kt < 2; kt++)
            qf[mt2][kt] = *(const shortx8*)(QK +
                (size_t)(b * L1D + q0 + wid * 32 + mt2 * 16 + c) * OHD + h * 64 + kt * 32 + qd * 8);

    floatx4 o[2][4] = {};
    float psum[2][4] = {};

    const unsigned short* Kbase = QK + HD + (size_t)b * L2D * OHD + h * 64;
    const unsigned short* Vbase = Vt + (size_t)bh * 64 * L2D;
    const float* bb = biasf + b * L2D;

    // staging indices (loop-invariant)
    int idxa = tid, idxb = 256 + tid;
    int rowa = idxa >> 3, sca = ((idxa & 7) ^ (rowa & 7)) * 8;
    int rowb = idxb >> 3, scb = ((idxb & 7) ^ (rowb & 7)) * 8;
    const int swz8 = c & 7;  // frag-read xor

    for (int kv0 = 0; kv0 < L2D; kv0 += 64) {
        gl2lds16(Kbase + (size_t)(kv0 + rowa) * OHD + sca, &Ks[idxa * 8]);
        gl2lds16(Vbase + (size_t)rowa * L2D + kv0 + sca, &Vs[idxa * 8]);
        gl2lds16(Kbase + (size_t)(kv0 + rowb) * OHD + scb, &Ks[idxb * 8]);
        gl2lds16(Vbase + (size_t)rowb * L2D + kv0 + scb, &Vs[idxb * 8]);
        __syncthreads();

        float bv[4];
        for (int nt = 0; nt < 4; nt++) bv[nt] = bb[kv0 + nt * 16 + c];

        for (int mt2 = 0; mt2 < 2; mt2++) {
            for (int nt = 0; nt < 4; nt++) {
                floatx4 z = {};
                for (int kt = 0; kt < 2; kt++) {
                    shortx8 kf = *(shortx8*)(&Ks[(nt * 16 + c) * 64 + ((kt * 4 + qd) ^ swz8) * 8]);
                    z = __builtin_amdgcn_mfma_f32_16x16x32_bf16(qf[mt2][kt], kf, z, 0, 0, 0);
                }
                for (int r = 0; r < 4; r++) {
                    float p = EXP2(z[r] + bv[nt]);
                    psum[mt2][r] += p;
                    Ps[wid][(mt2 * 16 + qd * 4 + r) * 72 + nt * 16 + c] = f2bf_fast(p);
                }
            }
        }
        for (int mt2 = 0; mt2 < 2; mt2++) {
            shortx8 pf[2];
            for (int kt = 0; kt < 2; kt++)
                pf[kt] = *(shortx8*)(&Ps[wid][(mt2 * 16 + c) * 72 + kt * 32 + qd * 8]);
            for (int nt = 0; nt < 4; nt++)
                for (int kt = 0; kt < 2; kt++) {
                    shortx8 vf = *(shortx8*)(&Vs[(nt * 16 + c) * 64 + ((kt * 4 + qd) ^ swz8) * 8]);
                    o[mt2][nt] = __builtin_amdgcn_mfma_f32_16x16x32_bf16(pf[kt], vf, o[mt2][nt], 0, 0, 0);
                }
        }
        __syncthreads();
    }

    for (int mt2 = 0; mt2 < 2; mt2++)
        for (int r = 0; r < 4; r++) {
            float l = psum[mt2][r];
            for (int off = 1; off < 16; off <<= 1)
                l += __shfl_xor(l, off, 64);
            float inv = 1.0f / l;
            size_t rowbase = ((size_t)b * L1D + q0 + wid * 32 + mt2 * 16 + qd * 4 + r) * HD + h * 64;
            for (int nt = 0; nt < 4; nt++)
                out[rowbase + nt * 16 + c] = o[mt2][nt][r] * inv;
        }
}

// ---------------------------------------------------------------------------
extern "C" void kernel_launch(void* const* d_in, const int* in_sizes, int n_in,
                              void* d_out, int out_size, void* d_ws, size_t ws_size,
                              hipStream_t stream) {
    const float* x  = (const float*)d_in[0];
    const float* y  = (const float*)d_in[1];
    const int*  ym  = (const int*)d_in[2];
    const float* Wq = (const float*)d_in[3];
    const float* bq = (const float*)d_in[4];
    const float* Wk = (const float*)d_in[5];
    const float* bk = (const float*)d_in[6];
    const float* Wv = (const float*)d_in[7];
    const float* bv = (const float*)d_in[8];
    float* outp = (float*)d_out;

    const size_t M = (size_t)BATCH * L1D;      // 16384
    const size_t T = M * HD;                   // 16.78M
    unsigned short* Obuf = (unsigned short*)d_ws;     // M*3072 (QKV fused)
    unsigned short* xb   = Obuf + M * OHD;            // T ; reused as Vt after gemm
    unsigned short* yb   = xb + T;                    // T
    unsigned short* Wt   = yb + T;                    // 3072*1024
    float* biasf         = (float*)(Wt + (size_t)OHD * DIN);
    // total ~174 MB

    const float QSCALE = 0.125f * 1.44269504088896340736f;  // 1/sqrt(64)*log2(e)

    prep_kernel<<<2 * NCVT + (BATCH * L2D) / 256, 256, 0, stream>>>(x, y, xb, yb, ym, biasf);
    wt_kernel<<<dim3(HD / 32, DIN / 32, 3), dim3(32, 8), 0, stream>>>(Wq, Wk, Wv, Wt);
    gemm_kernel<<<dim3(OHD / 256, M / 256), 512, 0, stream>>>(xb, yb, Wt, bq, bk, bv, Obuf, QSCALE);
    vt_kernel<<<dim3(L2D / 64, BATCH * NH), 256, 0, stream>>>(Obuf + 2 * HD, xb);
    attn_kernel<<<dim3(L1D / 128, BATCH * NH), 256, 0, stream>>>(Obuf, xb, biasf, outp);
}

// Round 5
// 412.170 us; speedup vs baseline: 1.0415x; 1.0018x over previous
//
#include <hip/hip_runtime.h>
#include <hip/hip_bf16.h>

// MultiAttnMatch — cross attention
// B=16, L1=1024, L2=1024, DIN=1024, H=16, DK=DV=64
#define BATCH 16
#define L1D 1024
#define L2D 1024
#define DIN 1024
#define NH 16
#define HD 1024   // NH*DK = NH*DV (output row stride)
#define OHD 3072  // fused QKV row stride

typedef __attribute__((ext_vector_type(4))) float floatx4;
typedef __attribute__((ext_vector_type(8))) short shortx8;
typedef __attribute__((ext_vector_type(8))) unsigned short ushortx8;

#if __has_builtin(__builtin_amdgcn_exp2f)
#define EXP2(x) __builtin_amdgcn_exp2f(x)
#else
#define EXP2(x) exp2f(x)
#endif

static __device__ __forceinline__ unsigned short f2bf(float f) {  // RNE
    union { float f; unsigned u; } v; v.f = f;
    unsigned r = v.u + 0x7fff + ((v.u >> 16) & 1);
    return (unsigned short)(r >> 16);
}
static __device__ __forceinline__ unsigned short f2bf_fast(float f) {  // round-half-up
    union { float f; unsigned u; } v; v.f = f;
    return (unsigned short)((v.u + 0x8000u) >> 16);
}

#define GLOBAL_AS __attribute__((address_space(1)))
#define LDS_AS __attribute__((address_space(3)))
static __device__ __forceinline__ void gl2lds16(const unsigned short* g, unsigned short* l) {
    __builtin_amdgcn_global_load_lds((const GLOBAL_AS unsigned int*)g,
                                     (LDS_AS unsigned int*)l, 16, 0, 0);
}

// compiler-only memory fence: pins LDS/VMEM op order across barriers without
// emitting any waitcnt (waits stay dependency-driven / counted).
#define CFENCE() asm volatile("" ::: "memory")

// ---------------------------------------------------------------------------
// prep: cvt x -> xb, cvt y -> yb (fp32->bf16, 8/thread), mask -> float bias
// ---------------------------------------------------------------------------
#define NCVT 8192  // T/2048 blocks per tensor
__global__ void prep_kernel(const float* __restrict__ x, const float* __restrict__ y,
                            unsigned short* __restrict__ xb, unsigned short* __restrict__ yb,
                            const int* __restrict__ ym, float* __restrict__ biasf) {
    int bid = blockIdx.x;
    if (bid < 2 * NCVT) {
        const float* in = bid < NCVT ? x : y;
        unsigned short* o = bid < NCVT ? xb : yb;
        int bb = bid < NCVT ? bid : bid - NCVT;
        size_t i = ((size_t)bb * 256 + threadIdx.x) * 8;
        float4 a = *(const float4*)(in + i);
        float4 b = *(const float4*)(in + i + 4);
        ushortx8 v;
        v[0] = f2bf(a.x); v[1] = f2bf(a.y); v[2] = f2bf(a.z); v[3] = f2bf(a.w);
        v[4] = f2bf(b.x); v[5] = f2bf(b.y); v[6] = f2bf(b.z); v[7] = f2bf(b.w);
        *(ushortx8*)(o + i) = v;
    } else {
        int i = (bid - 2 * NCVT) * 256 + threadIdx.x;
        biasf[i] = ym[i] ? -INFINITY : 0.0f;
    }
}

// ---------------------------------------------------------------------------
// W [DIN][HD] fp32 -> Wt [3*HD][DIN] bf16 (transpose + convert), z = section
// ---------------------------------------------------------------------------
__global__ void wt_kernel(const float* __restrict__ Wq, const float* __restrict__ Wk,
                          const float* __restrict__ Wv, unsigned short* __restrict__ Wt) {
    __shared__ float tile[32][33];
    const float* W = blockIdx.z == 0 ? Wq : (blockIdx.z == 1 ? Wk : Wv);
    unsigned short* dst = Wt + (size_t)blockIdx.z * HD * DIN;
    int bx = blockIdx.x, by = blockIdx.y;
    int tx = threadIdx.x, ty = threadIdx.y;
    for (int i = 0; i < 4; i++)
        tile[ty + i * 8][tx] = W[(size_t)(by * 32 + ty + i * 8) * HD + bx * 32 + tx];
    __syncthreads();
    for (int i = 0; i < 4; i++)
        dst[(size_t)(bx * 32 + ty + i * 8) * DIN + by * 32 + tx] = f2bf(tile[tx][ty + i * 8]);
}

// ---------------------------------------------------------------------------
// Fused QKV GEMM — 256x256 tile, BK=64, 8 waves (2Mx4N), 8-phase schedule.
// Counted vmcnt(4) at phases 4/8 (never 0 mid-loop), raw s_barrier, chunk-XOR
// swizzled LDS. ds_read->MFMA waits are DEPENDENCY-DRIVEN (no forced
// lgkmcnt(0) drain): plain C++ LDS loads let the compiler emit counted
// lgkmcnt per MFMA, so MFMA of early-arriving frags overlaps the LDS burst.
// ---------------------------------------------------------------------------
__global__ __launch_bounds__(512, 2) void gemm_kernel(
    const unsigned short* __restrict__ xb, const unsigned short* __restrict__ yb,
    const unsigned short* __restrict__ Wt,
    const float* __restrict__ bq, const float* __restrict__ bk, const float* __restrict__ bvp,
    unsigned short* __restrict__ Out, float qscale)
{
    __shared__ unsigned short As[2][256 * 64];   // 64 KB (double-buffered K-tiles)
    __shared__ unsigned short Bs[2][256 * 64];   // 64 KB

    // XCD-aware remap: nwg = 12*64 = 768 = 96/XCD (bijective, 768%8==0)
    int f = blockIdx.y * gridDim.x + blockIdx.x;
    int swz = (f & 7) * 96 + (f >> 3);
    const int n0 = (swz % 12) * 256;
    const int m0 = (swz / 12) * 256;
    const int sec = n0 >> 10;
    const unsigned short* Aptr = (sec == 0) ? xb : yb;
    const float* bias = (sec == 0) ? bq : (sec == 1 ? bk : bvp);
    const float scale = (sec == 0) ? qscale : 1.0f;

    const int tid = threadIdx.x;
    const int wid = tid >> 6, lane = tid & 63;
    const int c = lane & 15, qd = lane >> 4;
    const int cswz = c & 7;                 // fragment-read chunk XOR
    const int R0 = (wid >> 2) * 128;        // wave M offset (2 wave-rows)
    const int C0 = (wid & 3) * 64;          // wave N offset (4 wave-cols)

    // staging thread map: one gl2lds16 covers 64 rows x 64 cols (8KB/512thr)
    const int srow = tid >> 3;              // 0..63
    const int sphys = tid & 7;              // phys 16B chunk in row
    const int scol = (sphys ^ (srow & 7)) * 8;  // pre-swizzled global col

    floatx4 acc[8][4] = {};
    shortx8 a[4][2];            // current A half (4 m-frags x 2 k-chunks)
    shortx8 b0[2][2], b1[2][2]; // both B halves of current K-tile

    auto dsrdA = [&](int mq, const unsigned short* buf) {
#pragma unroll
        for (int i = 0; i < 4; i++)
#pragma unroll
            for (int kk = 0; kk < 2; kk++)
                a[i][kk] = *(const shortx8*)&buf[(R0 + mq * 64 + i * 16 + c) * 64 +
                                                 (((kk * 4 + qd) ^ cswz) * 8)];
    };
    auto dsrdB = [&](shortx8 (&bt)[2][2], int nq, const unsigned short* buf) {
#pragma unroll
        for (int j = 0; j < 2; j++)
#pragma unroll
            for (int kk = 0; kk < 2; kk++)
                bt[j][kk] = *(const shortx8*)&buf[(C0 + (nq * 2 + j) * 16 + c) * 64 +
                                                  (((kk * 4 + qd) ^ cswz) * 8)];
    };
    auto mfmaQ = [&](int mq, int nq, shortx8 (&bt)[2][2]) {
        __builtin_amdgcn_s_setprio(1);
#pragma unroll
        for (int kk = 0; kk < 2; kk++)
#pragma unroll
            for (int i = 0; i < 4; i++)
#pragma unroll
                for (int j = 0; j < 2; j++)
                    acc[mq * 4 + i][nq * 2 + j] = __builtin_amdgcn_mfma_f32_16x16x32_bf16(
                        a[i][kk], bt[j][kk], acc[mq * 4 + i][nq * 2 + j], 0, 0, 0);
        __builtin_amdgcn_s_setprio(0);
    };
    auto stageA = [&](unsigned short* dst, int h, int kt) {  // one half-tile (2 loads)
        const unsigned short* g = Aptr + (size_t)(m0 + h * 128 + srow) * DIN + kt * 64 + scol;
        unsigned short* l = dst + (h * 128 + srow) * 64 + sphys * 8;
        gl2lds16(g, l);
        gl2lds16(g + (size_t)64 * DIN, l + 64 * 64);
    };
    auto stageB = [&](unsigned short* dst, int h, int kt) {
        const unsigned short* g = Wt + (size_t)(n0 + h * 128 + srow) * DIN + kt * 64 + scol;
        unsigned short* l = dst + (h * 128 + srow) * 64 + sphys * 8;
        gl2lds16(g, l);
        gl2lds16(g + (size_t)64 * DIN, l + 64 * 64);
    };

    // bias preload FIRST + drain, so no stray VMEM pollutes vmcnt counting
    float biasv[4];
#pragma unroll
    for (int nf = 0; nf < 4; nf++)
        biasv[nf] = bias[((n0 & 1023) + C0 + nf * 16 + c) & 1023];
    asm volatile("s_waitcnt vmcnt(0)" ::: "memory");

    // prologue: tile0 full (buf0, 8 loads) + tile1 B (buf1, 4 loads)
    stageB(Bs[0], 0, 0); stageB(Bs[0], 1, 0);
    stageA(As[0], 0, 0); stageA(As[0], 1, 0);
    stageB(Bs[1], 0, 1); stageB(Bs[1], 1, 1);
    asm volatile("s_waitcnt vmcnt(4)" ::: "memory");   // tile0 arrived
    CFENCE(); __builtin_amdgcn_s_barrier(); CFENCE();

    // 16 K-tiles, 2 per iteration (even->buf0, odd->buf1)
    for (int it = 0; it < 8; ++it) {
        const int kt1 = 2 * it + 1;       // odd tile read this iter (buf1)
        const int ktp = 2 * it + 2;       // prefetched even tile (buf0)
        const bool pf = (it < 7);

        // P1: tile2i (buf0), quadrant (mh0,nh0); stage tile(2i+1) A half0
        dsrdA(0, As[0]); dsrdB(b0, 0, Bs[0]);
        stageA(As[1], 0, kt1);
        CFENCE(); __builtin_amdgcn_s_barrier(); CFENCE();
        mfmaQ(0, 0, b0);
        CFENCE(); __builtin_amdgcn_s_barrier(); CFENCE();

        // P2: (mh0,nh1); stage tile(2i+1) A half1
        dsrdB(b1, 1, Bs[0]);
        stageA(As[1], 1, kt1);
        CFENCE(); __builtin_amdgcn_s_barrier(); CFENCE();
        mfmaQ(0, 1, b1);
        CFENCE(); __builtin_amdgcn_s_barrier(); CFENCE();

        // P3: (mh1,nh1); buf0-B free since end P2 -> stage tile(2i+2) B half0
        dsrdA(1, As[0]);
        if (pf) stageB(Bs[0], 0, ktp);
        CFENCE(); __builtin_amdgcn_s_barrier(); CFENCE();
        mfmaQ(1, 1, b1);
        CFENCE(); __builtin_amdgcn_s_barrier(); CFENCE();

        // P4: (mh1,nh0); stage tile(2i+2) B half1; wait: tile(2i+1) complete
        if (pf) stageB(Bs[0], 1, ktp);
        CFENCE(); __builtin_amdgcn_s_barrier(); CFENCE();
        mfmaQ(1, 0, b0);
        if (pf) asm volatile("s_waitcnt vmcnt(4)" ::: "memory");
        else    asm volatile("s_waitcnt vmcnt(0)" ::: "memory");
        CFENCE(); __builtin_amdgcn_s_barrier(); CFENCE();

        // P5: tile2i+1 (buf1), (mh0,nh0); buf0-A free since P3 -> stage A half0
        dsrdA(0, As[1]); dsrdB(b0, 0, Bs[1]);
        if (pf) stageA(As[0], 0, ktp);
        CFENCE(); __builtin_amdgcn_s_barrier(); CFENCE();
        mfmaQ(0, 0, b0);
        CFENCE(); __builtin_amdgcn_s_barrier(); CFENCE();

        // P6: (mh0,nh1); stage tile(2i+2) A half1
        dsrdB(b1, 1, Bs[1]);
        if (pf) stageA(As[0], 1, ktp);
        CFENCE(); __builtin_amdgcn_s_barrier(); CFENCE();
        mfmaQ(0, 1, b1);
        CFENCE(); __builtin_amdgcn_s_barrier(); CFENCE();

        // P7: (mh1,nh1); buf1-B free since P6 -> stage tile(2i+3) B half0
        dsrdA(1, As[1]);
        if (pf) stageB(Bs[1], 0, ktp + 1);
        CFENCE(); __builtin_amdgcn_s_barrier(); CFENCE();
        mfmaQ(1, 1, b1);
        CFENCE(); __builtin_amdgcn_s_barrier(); CFENCE();

        // P8: (mh1,nh0); stage tile(2i+3) B half1; wait: tile(2i+2) complete
        if (pf) stageB(Bs[1], 1, ktp + 1);
        CFENCE(); __builtin_amdgcn_s_barrier(); CFENCE();
        mfmaQ(1, 0, b0);
        if (pf) asm volatile("s_waitcnt vmcnt(4)" ::: "memory");
        CFENCE(); __builtin_amdgcn_s_barrier(); CFENCE();
    }

    // epilogue: bias + scale + bf16 convert, scalar stores (no LDS deps)
#pragma unroll
    for (int nf = 0; nf < 4; nf++) {
        const int gn = n0 + C0 + nf * 16 + c;
        const float bvv = biasv[nf];
#pragma unroll
        for (int mf = 0; mf < 8; mf++)
#pragma unroll
            for (int r = 0; r < 4; r++) {
                const int gm = m0 + R0 + mf * 16 + qd * 4 + r;
                Out[(size_t)gm * OHD + gn] = f2bf((acc[mf][nf][r] + bvv) * scale);
            }
    }
}

// ---------------------------------------------------------------------------
// V (Obuf cols 2048..3071, stride 3072) -> Vt [(b*16+h)*64+dv][l2] bf16
// ---------------------------------------------------------------------------
__global__ void vt_kernel(const unsigned short* __restrict__ V,
                          unsigned short* __restrict__ Vt) {
    __shared__ unsigned short t[64][72];
    const int l20 = blockIdx.x * 64;
    const int bh  = blockIdx.y;
    const int b = bh >> 4, h = bh & 15;
    const int tid = threadIdx.x;
    for (int i = 0; i < 2; i++) {
        int idx = i * 256 + tid;
        int row = idx >> 3, col = (idx & 7) * 8;
        *(ushortx8*)(&t[row][col]) =
            *(const ushortx8*)(V + (size_t)(b * L2D + l20 + row) * OHD + h * 64 + col);
    }
    __syncthreads();
    for (int i = 0; i < 2; i++) {
        int idx = i * 256 + tid;
        int dv = idx >> 3, col = (idx & 7) * 8;
        ushortx8 v;
        for (int j = 0; j < 8; j++) v[j] = t[col + j][dv];
        *(ushortx8*)(Vt + (size_t)(bh * 64 + dv) * L2D + l20 + col) = v;
    }
}

// ---------------------------------------------------------------------------
// Attention: no-max exp2 softmax, Q-block 128, KV tiles 64.
// K/V staged via global_load_lds with XOR chunk swizzle (2-way banks).
// XCD-aware block remap so the 8 q-blocks of one (b,h) share one L2.
// ---------------------------------------------------------------------------
__global__ __launch_bounds__(256, 4) void attn_kernel(
    const unsigned short* __restrict__ QK,   // Obuf: Q = col 0, K = col 1024
    const unsigned short* __restrict__ Vt, const float* __restrict__ biasf,
    float* __restrict__ out)
{
    __shared__ unsigned short Ks[64 * 64];
    __shared__ unsigned short Vs[64 * 64];
    __shared__ unsigned short Ps[4][32 * 72];

    // remap: same-XCD blocks (flat%8) share bh
    int f = blockIdx.y * gridDim.x + blockIdx.x;   // 0..2047
    int bh = (f & 7) * 32 + (f >> 6);
    int q0 = ((f >> 3) & 7) * 128;
    const int b = bh >> 4, h = bh & 15;
    const int tid = threadIdx.x, wid = tid >> 6, lane = tid & 63;
    const int c = lane & 15, qd = lane >> 4;

    // Q A-fragments (Q pre-scaled by 0.125*log2e in GEMM epilogue)
    shortx8 qf[2][2];
    for (int mt2 = 0; mt2 < 2; mt2++)
        for (int kt = 0; kt < 2; kt++)
            qf[mt2][kt] = *(const shortx8*)(QK +
                (size_t)(b * L1D + q0 + wid * 32 + mt2 * 16 + c) * OHD + h * 64 + kt * 32 + qd * 8);

    floatx4 o[2][4] = {};
    float psum[2][4] = {};

    const unsigned short* Kbase = QK + HD + (size_t)b * L2D * OHD + h * 64;
    const unsigned short* Vbase = Vt + (size_t)bh * 64 * L2D;
    const float* bb = biasf + b * L2D;

    // staging indices (loop-invariant)
    int idxa = tid, idxb = 256 + tid;
    int rowa = idxa >> 3, sca = ((idxa & 7) ^ (rowa & 7)) * 8;
    int rowb = idxb >> 3, scb = ((idxb & 7) ^ (rowb & 7)) * 8;
    const int swz8 = c & 7;  // frag-read xor

    for (int kv0 = 0; kv0 < L2D; kv0 += 64) {
        gl2lds16(Kbase + (size_t)(kv0 + rowa) * OHD + sca, &Ks[idxa * 8]);
        gl2lds16(Vbase + (size_t)rowa * L2D + kv0 + sca, &Vs[idxa * 8]);
        gl2lds16(Kbase + (size_t)(kv0 + rowb) * OHD + scb, &Ks[idxb * 8]);
        gl2lds16(Vbase + (size_t)rowb * L2D + kv0 + scb, &Vs[idxb * 8]);
        __syncthreads();

        float bv[4];
        for (int nt = 0; nt < 4; nt++) bv[nt] = bb[kv0 + nt * 16 + c];

        for (int mt2 = 0; mt2 < 2; mt2++) {
            for (int nt = 0; nt < 4; nt++) {
                floatx4 z = {};
                for (int kt = 0; kt < 2; kt++) {
                    shortx8 kf = *(shortx8*)(&Ks[(nt * 16 + c) * 64 + ((kt * 4 + qd) ^ swz8) * 8]);
                    z = __builtin_amdgcn_mfma_f32_16x16x32_bf16(qf[mt2][kt], kf, z, 0, 0, 0);
                }
                for (int r = 0; r < 4; r++) {
                    float p = EXP2(z[r] + bv[nt]);
                    psum[mt2][r] += p;
                    Ps[wid][(mt2 * 16 + qd * 4 + r) * 72 + nt * 16 + c] = f2bf_fast(p);
                }
            }
        }
        for (int mt2 = 0; mt2 < 2; mt2++) {
            shortx8 pf[2];
            for (int kt = 0; kt < 2; kt++)
                pf[kt] = *(shortx8*)(&Ps[wid][(mt2 * 16 + c) * 72 + kt * 32 + qd * 8]);
            for (int nt = 0; nt < 4; nt++)
                for (int kt = 0; kt < 2; kt++) {
                    shortx8 vf = *(shortx8*)(&Vs[(nt * 16 + c) * 64 + ((kt * 4 + qd) ^ swz8) * 8]);
                    o[mt2][nt] = __builtin_amdgcn_mfma_f32_16x16x32_bf16(pf[kt], vf, o[mt2][nt], 0, 0, 0);
                }
        }
        __syncthreads();
    }

    for (int mt2 = 0; mt2 < 2; mt2++)
        for (int r = 0; r < 4; r++) {
            float l = psum[mt2][r];
            for (int off = 1; off < 16; off <<= 1)
                l += __shfl_xor(l, off, 64);
            float inv = 1.0f / l;
            size_t rowbase = ((size_t)b * L1D + q0 + wid * 32 + mt2 * 16 + qd * 4 + r) * HD + h * 64;
            for (int nt = 0; nt < 4; nt++)
                out[rowbase + nt * 16 + c] = o[mt2][nt][r] * inv;
        }
}

// ---------------------------------------------------------------------------
extern "C" void kernel_launch(void* const* d_in, const int* in_sizes, int n_in,
                              void* d_out, int out_size, void* d_ws, size_t ws_size,
                              hipStream_t stream) {
    const float* x  = (const float*)d_in[0];
    const float* y  = (const float*)d_in[1];
    const int*  ym  = (const int*)d_in[2];
    const float* Wq = (const float*)d_in[3];
    const float* bq = (const float*)d_in[4];
    const float* Wk = (const float*)d_in[5];
    const float* bk = (const float*)d_in[6];
    const float* Wv = (const float*)d_in[7];
    const float* bv = (const float*)d_in[8];
    float* outp = (float*)d_out;

    const size_t M = (size_t)BATCH * L1D;      // 16384
    const size_t T = M * HD;                   // 16.78M
    unsigned short* Obuf = (unsigned short*)d_ws;     // M*3072 (QKV fused)
    unsigned short* xb   = Obuf + M * OHD;            // T ; reused as Vt after gemm
    unsigned short* yb   = xb + T;                    // T
    unsigned short* Wt   = yb + T;                    // 3072*1024
    float* biasf         = (float*)(Wt + (size_t)OHD * DIN);
    // total ~174 MB

    const float QSCALE = 0.125f * 1.44269504088896340736f;  // 1/sqrt(64)*log2(e)

    prep_kernel<<<2 * NCVT + (BATCH * L2D) / 256, 256, 0, stream>>>(x, y, xb, yb, ym, biasf);
    wt_kernel<<<dim3(HD / 32, DIN / 32, 3), dim3(32, 8), 0, stream>>>(Wq, Wk, Wv, Wt);
    gemm_kernel<<<dim3(OHD / 256, M / 256), 512, 0, stream>>>(xb, yb, Wt, bq, bk, bv, Obuf, QSCALE);
    vt_kernel<<<dim3(L2D / 64, BATCH * NH), 256, 0, stream>>>(Obuf + 2 * HD, xb);
    attn_kernel<<<dim3(L1D / 128, BATCH * NH), 256, 0, stream>>>(Obuf, xb, biasf, outp);
}

// Round 6
// 398.269 us; speedup vs baseline: 1.0779x; 1.0349x over previous
//
#include <hip/hip_runtime.h>
#include <hip/hip_bf16.h>

// MultiAttnMatch — cross attention
// B=16, L1=1024, L2=1024, DIN=1024, H=16, DK=DV=64
#define BATCH 16
#define L1D 1024
#define L2D 1024
#define DIN 1024
#define NH 16
#define HD 1024   // NH*DK = NH*DV (output row stride)
#define OHD 3072  // fused QKV row stride

typedef __attribute__((ext_vector_type(4))) float floatx4;
typedef __attribute__((ext_vector_type(8))) short shortx8;
typedef __attribute__((ext_vector_type(8))) unsigned short ushortx8;

#if __has_builtin(__builtin_amdgcn_exp2f)
#define EXP2(x) __builtin_amdgcn_exp2f(x)
#else
#define EXP2(x) exp2f(x)
#endif

static __device__ __forceinline__ unsigned short f2bf(float f) {  // RNE
    union { float f; unsigned u; } v; v.f = f;
    unsigned r = v.u + 0x7fff + ((v.u >> 16) & 1);
    return (unsigned short)(r >> 16);
}
static __device__ __forceinline__ unsigned short f2bf_fast(float f) {  // round-half-up
    union { float f; unsigned u; } v; v.f = f;
    return (unsigned short)((v.u + 0x8000u) >> 16);
}

#define GLOBAL_AS __attribute__((address_space(1)))
#define LDS_AS __attribute__((address_space(3)))
static __device__ __forceinline__ void gl2lds16(const unsigned short* g, unsigned short* l) {
    __builtin_amdgcn_global_load_lds((const GLOBAL_AS unsigned int*)g,
                                     (LDS_AS unsigned int*)l, 16, 0, 0);
}

// compiler-only memory fence: pins LDS/VMEM op order across barriers without
// emitting any waitcnt (waits stay dependency-driven / counted).
#define CFENCE() asm volatile("" ::: "memory")

// ---------------------------------------------------------------------------
// prep: cvt x -> xb, cvt y -> yb (fp32->bf16, 8/thread), mask -> float bias
// ---------------------------------------------------------------------------
#define NCVT 8192  // T/2048 blocks per tensor
__global__ void prep_kernel(const float* __restrict__ x, const float* __restrict__ y,
                            unsigned short* __restrict__ xb, unsigned short* __restrict__ yb,
                            const int* __restrict__ ym, float* __restrict__ biasf) {
    int bid = blockIdx.x;
    if (bid < 2 * NCVT) {
        const float* in = bid < NCVT ? x : y;
        unsigned short* o = bid < NCVT ? xb : yb;
        int bb = bid < NCVT ? bid : bid - NCVT;
        size_t i = ((size_t)bb * 256 + threadIdx.x) * 8;
        float4 a = *(const float4*)(in + i);
        float4 b = *(const float4*)(in + i + 4);
        ushortx8 v;
        v[0] = f2bf(a.x); v[1] = f2bf(a.y); v[2] = f2bf(a.z); v[3] = f2bf(a.w);
        v[4] = f2bf(b.x); v[5] = f2bf(b.y); v[6] = f2bf(b.z); v[7] = f2bf(b.w);
        *(ushortx8*)(o + i) = v;
    } else {
        int i = (bid - 2 * NCVT) * 256 + threadIdx.x;
        biasf[i] = ym[i] ? -INFINITY : 0.0f;
    }
}

// ---------------------------------------------------------------------------
// W [DIN][HD] fp32 -> Wt [3*HD][DIN] bf16 (transpose + convert), z = section
// ---------------------------------------------------------------------------
__global__ void wt_kernel(const float* __restrict__ Wq, const float* __restrict__ Wk,
                          const float* __restrict__ Wv, unsigned short* __restrict__ Wt) {
    __shared__ float tile[32][33];
    const float* W = blockIdx.z == 0 ? Wq : (blockIdx.z == 1 ? Wk : Wv);
    unsigned short* dst = Wt + (size_t)blockIdx.z * HD * DIN;
    int bx = blockIdx.x, by = blockIdx.y;
    int tx = threadIdx.x, ty = threadIdx.y;
    for (int i = 0; i < 4; i++)
        tile[ty + i * 8][tx] = W[(size_t)(by * 32 + ty + i * 8) * HD + bx * 32 + tx];
    __syncthreads();
    for (int i = 0; i < 4; i++)
        dst[(size_t)(bx * 32 + ty + i * 8) * DIN + by * 32 + tx] = f2bf(tile[tx][ty + i * 8]);
}

// ---------------------------------------------------------------------------
// Fused QKV GEMM — 256x256 tile, BK=64, 8 waves (2Mx4N), 8-phase schedule.
// Counted vmcnt(4) at phases 4/8 (never 0 mid-loop), raw s_barrier, chunk-XOR
// swizzled LDS, dependency-driven lgkmcnt.
// Epilogue: C-tile staged through the (now free) 128KB LDS so global stores
// are 16B/lane fully-coalesced (fixes the 2x WRITE_SIZE amplification that
// scalar 2B stores caused: 193MB -> ~105MB).
// ---------------------------------------------------------------------------
__global__ __launch_bounds__(512, 2) void gemm_kernel(
    const unsigned short* __restrict__ xb, const unsigned short* __restrict__ yb,
    const unsigned short* __restrict__ Wt,
    const float* __restrict__ bq, const float* __restrict__ bk, const float* __restrict__ bvp,
    unsigned short* __restrict__ Out, float qscale)
{
    __shared__ unsigned short As[2][256 * 64];   // 64 KB (double-buffered K-tiles)
    __shared__ unsigned short Bs[2][256 * 64];   // 64 KB

    // XCD-aware remap: nwg = 12*64 = 768 = 96/XCD (bijective, 768%8==0)
    int f = blockIdx.y * gridDim.x + blockIdx.x;
    int swz = (f & 7) * 96 + (f >> 3);
    const int n0 = (swz % 12) * 256;
    const int m0 = (swz / 12) * 256;
    const int sec = n0 >> 10;
    const unsigned short* Aptr = (sec == 0) ? xb : yb;
    const float* bias = (sec == 0) ? bq : (sec == 1 ? bk : bvp);
    const float scale = (sec == 0) ? qscale : 1.0f;

    const int tid = threadIdx.x;
    const int wid = tid >> 6, lane = tid & 63;
    const int c = lane & 15, qd = lane >> 4;
    const int cswz = c & 7;                 // fragment-read chunk XOR
    const int R0 = (wid >> 2) * 128;        // wave M offset (2 wave-rows)
    const int C0 = (wid & 3) * 64;          // wave N offset (4 wave-cols)

    // staging thread map: one gl2lds16 covers 64 rows x 64 cols (8KB/512thr)
    const int srow = tid >> 3;              // 0..63
    const int sphys = tid & 7;              // phys 16B chunk in row
    const int scol = (sphys ^ (srow & 7)) * 8;  // pre-swizzled global col

    floatx4 acc[8][4] = {};
    shortx8 a[4][2];            // current A half (4 m-frags x 2 k-chunks)
    shortx8 b0[2][2], b1[2][2]; // both B halves of current K-tile

    auto dsrdA = [&](int mq, const unsigned short* buf) {
#pragma unroll
        for (int i = 0; i < 4; i++)
#pragma unroll
            for (int kk = 0; kk < 2; kk++)
                a[i][kk] = *(const shortx8*)&buf[(R0 + mq * 64 + i * 16 + c) * 64 +
                                                 (((kk * 4 + qd) ^ cswz) * 8)];
    };
    auto dsrdB = [&](shortx8 (&bt)[2][2], int nq, const unsigned short* buf) {
#pragma unroll
        for (int j = 0; j < 2; j++)
#pragma unroll
            for (int kk = 0; kk < 2; kk++)
                bt[j][kk] = *(const shortx8*)&buf[(C0 + (nq * 2 + j) * 16 + c) * 64 +
                                                  (((kk * 4 + qd) ^ cswz) * 8)];
    };
    auto mfmaQ = [&](int mq, int nq, shortx8 (&bt)[2][2]) {
        __builtin_amdgcn_s_setprio(1);
#pragma unroll
        for (int kk = 0; kk < 2; kk++)
#pragma unroll
            for (int i = 0; i < 4; i++)
#pragma unroll
                for (int j = 0; j < 2; j++)
                    acc[mq * 4 + i][nq * 2 + j] = __builtin_amdgcn_mfma_f32_16x16x32_bf16(
                        a[i][kk], bt[j][kk], acc[mq * 4 + i][nq * 2 + j], 0, 0, 0);
        __builtin_amdgcn_s_setprio(0);
    };
    auto stageA = [&](unsigned short* dst, int h, int kt) {  // one half-tile (2 loads)
        const unsigned short* g = Aptr + (size_t)(m0 + h * 128 + srow) * DIN + kt * 64 + scol;
        unsigned short* l = dst + (h * 128 + srow) * 64 + sphys * 8;
        gl2lds16(g, l);
        gl2lds16(g + (size_t)64 * DIN, l + 64 * 64);
    };
    auto stageB = [&](unsigned short* dst, int h, int kt) {
        const unsigned short* g = Wt + (size_t)(n0 + h * 128 + srow) * DIN + kt * 64 + scol;
        unsigned short* l = dst + (h * 128 + srow) * 64 + sphys * 8;
        gl2lds16(g, l);
        gl2lds16(g + (size_t)64 * DIN, l + 64 * 64);
    };

    // bias preload FIRST + drain, so no stray VMEM pollutes vmcnt counting
    float biasv[4];
#pragma unroll
    for (int nf = 0; nf < 4; nf++)
        biasv[nf] = bias[((n0 & 1023) + C0 + nf * 16 + c) & 1023];
    asm volatile("s_waitcnt vmcnt(0)" ::: "memory");

    // prologue: tile0 full (buf0, 8 loads) + tile1 B (buf1, 4 loads)
    stageB(Bs[0], 0, 0); stageB(Bs[0], 1, 0);
    stageA(As[0], 0, 0); stageA(As[0], 1, 0);
    stageB(Bs[1], 0, 1); stageB(Bs[1], 1, 1);
    asm volatile("s_waitcnt vmcnt(4)" ::: "memory");   // tile0 arrived
    CFENCE(); __builtin_amdgcn_s_barrier(); CFENCE();

    // 16 K-tiles, 2 per iteration (even->buf0, odd->buf1)
    for (int it = 0; it < 8; ++it) {
        const int kt1 = 2 * it + 1;       // odd tile read this iter (buf1)
        const int ktp = 2 * it + 2;       // prefetched even tile (buf0)
        const bool pf = (it < 7);

        // P1: tile2i (buf0), quadrant (mh0,nh0); stage tile(2i+1) A half0
        dsrdA(0, As[0]); dsrdB(b0, 0, Bs[0]);
        stageA(As[1], 0, kt1);
        CFENCE(); __builtin_amdgcn_s_barrier(); CFENCE();
        mfmaQ(0, 0, b0);
        CFENCE(); __builtin_amdgcn_s_barrier(); CFENCE();

        // P2: (mh0,nh1); stage tile(2i+1) A half1
        dsrdB(b1, 1, Bs[0]);
        stageA(As[1], 1, kt1);
        CFENCE(); __builtin_amdgcn_s_barrier(); CFENCE();
        mfmaQ(0, 1, b1);
        CFENCE(); __builtin_amdgcn_s_barrier(); CFENCE();

        // P3: (mh1,nh1); buf0-B free since end P2 -> stage tile(2i+2) B half0
        dsrdA(1, As[0]);
        if (pf) stageB(Bs[0], 0, ktp);
        CFENCE(); __builtin_amdgcn_s_barrier(); CFENCE();
        mfmaQ(1, 1, b1);
        CFENCE(); __builtin_amdgcn_s_barrier(); CFENCE();

        // P4: (mh1,nh0); stage tile(2i+2) B half1; wait: tile(2i+1) complete
        if (pf) stageB(Bs[0], 1, ktp);
        CFENCE(); __builtin_amdgcn_s_barrier(); CFENCE();
        mfmaQ(1, 0, b0);
        if (pf) asm volatile("s_waitcnt vmcnt(4)" ::: "memory");
        else    asm volatile("s_waitcnt vmcnt(0)" ::: "memory");
        CFENCE(); __builtin_amdgcn_s_barrier(); CFENCE();

        // P5: tile2i+1 (buf1), (mh0,nh0); buf0-A free since P3 -> stage A half0
        dsrdA(0, As[1]); dsrdB(b0, 0, Bs[1]);
        if (pf) stageA(As[0], 0, ktp);
        CFENCE(); __builtin_amdgcn_s_barrier(); CFENCE();
        mfmaQ(0, 0, b0);
        CFENCE(); __builtin_amdgcn_s_barrier(); CFENCE();

        // P6: (mh0,nh1); stage tile(2i+2) A half1
        dsrdB(b1, 1, Bs[1]);
        if (pf) stageA(As[0], 1, ktp);
        CFENCE(); __builtin_amdgcn_s_barrier(); CFENCE();
        mfmaQ(0, 1, b1);
        CFENCE(); __builtin_amdgcn_s_barrier(); CFENCE();

        // P7: (mh1,nh1); buf1-B free since P6 -> stage tile(2i+3) B half0
        dsrdA(1, As[1]);
        if (pf) stageB(Bs[1], 0, ktp + 1);
        CFENCE(); __builtin_amdgcn_s_barrier(); CFENCE();
        mfmaQ(1, 1, b1);
        CFENCE(); __builtin_amdgcn_s_barrier(); CFENCE();

        // P8: (mh1,nh0); stage tile(2i+3) B half1; wait: tile(2i+2) complete
        if (pf) stageB(Bs[1], 1, ktp + 1);
        CFENCE(); __builtin_amdgcn_s_barrier(); CFENCE();
        mfmaQ(1, 0, b0);
        if (pf) asm volatile("s_waitcnt vmcnt(4)" ::: "memory");
        CFENCE(); __builtin_amdgcn_s_barrier(); CFENCE();
    }

    // ---- epilogue: C-tile through LDS -> coalesced 16B stores ----
    // After the last P8 barrier no wave touches As/Bs for the K-loop.
    // Per-wave 16KB region: waves 0-3 in As, 4-7 in Bs. Local [128][64] bf16,
    // col XOR'd by qd*16 (row-derived) to spread write banks.
    unsigned short* reg0 = (wid < 4) ? (&As[0][0] + wid * 8192)
                                     : (&Bs[0][0] + (wid - 4) * 8192);
#pragma unroll
    for (int mf = 0; mf < 8; mf++)
#pragma unroll
        for (int r = 0; r < 4; r++) {
            const int lrow = mf * 16 + qd * 4 + r;
#pragma unroll
            for (int nf = 0; nf < 4; nf++) {
                const int lcol = (nf * 16 + c) ^ (qd * 16);
                reg0[lrow * 64 + lcol] = f2bf((acc[mf][nf][r] + biasv[nf]) * scale);
            }
        }
    __syncthreads();
    // read back coalesced: 16 passes, each 16 rows x 512B contiguous
#pragma unroll
    for (int p = 0; p < 16; p++) {
        const int gr = p * 16 + (tid >> 5);          // tile row 0..255
        const int gc8 = (tid & 31) * 8;              // tile col (8-col chunk)
        const int wr = ((gr >> 7) << 2) + (gc8 >> 6);
        const unsigned short* rg = (wr < 4) ? (&As[0][0] + wr * 8192)
                                            : (&Bs[0][0] + (wr - 4) * 8192);
        const int lrow = gr & 127;
        const int lcol = (gc8 & 63) ^ (((lrow >> 2) & 3) * 16);
        ushortx8 vv = *(const ushortx8*)&rg[lrow * 64 + lcol];
        *(ushortx8*)(Out + (size_t)(m0 + gr) * OHD + n0 + gc8) = vv;
    }
}

// ---------------------------------------------------------------------------
// V (Obuf cols 2048..3071, stride 3072) -> Vt [(b*16+h)*64+dv][l2] bf16
// ---------------------------------------------------------------------------
__global__ void vt_kernel(const unsigned short* __restrict__ V,
                          unsigned short* __restrict__ Vt) {
    __shared__ unsigned short t[64][72];
    const int l20 = blockIdx.x * 64;
    const int bh  = blockIdx.y;
    const int b = bh >> 4, h = bh & 15;
    const int tid = threadIdx.x;
    for (int i = 0; i < 2; i++) {
        int idx = i * 256 + tid;
        int row = idx >> 3, col = (idx & 7) * 8;
        *(ushortx8*)(&t[row][col]) =
            *(const ushortx8*)(V + (size_t)(b * L2D + l20 + row) * OHD + h * 64 + col);
    }
    __syncthreads();
    for (int i = 0; i < 2; i++) {
        int idx = i * 256 + tid;
        int dv = idx >> 3, col = (idx & 7) * 8;
        ushortx8 v;
        for (int j = 0; j < 8; j++) v[j] = t[col + j][dv];
        *(ushortx8*)(Vt + (size_t)(bh * 64 + dv) * L2D + l20 + col) = v;
    }
}

// ---------------------------------------------------------------------------
// Attention: no-max exp2 softmax, Q-block 128, KV tiles 64.
// K/V staged via global_load_lds with XOR chunk swizzle (2-way banks).
// XCD-aware block remap so the 8 q-blocks of one (b,h) share one L2.
// ---------------------------------------------------------------------------
__global__ __launch_bounds__(256, 4) void attn_kernel(
    const unsigned short* __restrict__ QK,   // Obuf: Q = col 0, K = col 1024
    const unsigned short* __restrict__ Vt, const float* __restrict__ biasf,
    float* __restrict__ out)
{
    __shared__ unsigned short Ks[64 * 64];
    __shared__ unsigned short Vs[64 * 64];
    __shared__ unsigned short Ps[4][32 * 72];

    // remap: same-XCD blocks (flat%8) share bh
    int f = blockIdx.y * gridDim.x + blockIdx.x;   // 0..2047
    int bh = (f & 7) * 32 + (f >> 6);
    int q0 = ((f >> 3) & 7) * 128;
    const int b = bh >> 4, h = bh & 15;
    const int tid = threadIdx.x, wid = tid >> 6, lane = tid & 63;
    const int c = lane & 15, qd = lane >> 4;

    // Q A-fragments (Q pre-scaled by 0.125*log2e in GEMM epilogue)
    shortx8 qf[2][2];
    for (int mt2 = 0; mt2 < 2; mt2++)
        for (int kt = 0; kt < 2; kt++)
            qf[mt2][kt] = *(const shortx8*)(QK +
                (size_t)(b * L1D + q0 + wid * 32 + mt2 * 16 + c) * OHD + h * 64 + kt * 32 + qd * 8);

    floatx4 o[2][4] = {};
    float psum[2][4] = {};

    const unsigned short* Kbase = QK + HD + (size_t)b * L2D * OHD + h * 64;
    const unsigned short* Vbase = Vt + (size_t)bh * 64 * L2D;
    const float* bb = biasf + b * L2D;

    // staging indices (loop-invariant)
    int idxa = tid, idxb = 256 + tid;
    int rowa = idxa >> 3, sca = ((idxa & 7) ^ (rowa & 7)) * 8;
    int rowb = idxb >> 3, scb = ((idxb & 7) ^ (rowb & 7)) * 8;
    const int swz8 = c & 7;  // frag-read xor

    for (int kv0 = 0; kv0 < L2D; kv0 += 64) {
        gl2lds16(Kbase + (size_t)(kv0 + rowa) * OHD + sca, &Ks[idxa * 8]);
        gl2lds16(Vbase + (size_t)rowa * L2D + kv0 + sca, &Vs[idxa * 8]);
        gl2lds16(Kbase + (size_t)(kv0 + rowb) * OHD + scb, &Ks[idxb * 8]);
        gl2lds16(Vbase + (size_t)rowb * L2D + kv0 + scb, &Vs[idxb * 8]);
        __syncthreads();

        float bv[4];
        for (int nt = 0; nt < 4; nt++) bv[nt] = bb[kv0 + nt * 16 + c];

        for (int mt2 = 0; mt2 < 2; mt2++) {
            for (int nt = 0; nt < 4; nt++) {
                floatx4 z = {};
                for (int kt = 0; kt < 2; kt++) {
                    shortx8 kf = *(shortx8*)(&Ks[(nt * 16 + c) * 64 + ((kt * 4 + qd) ^ swz8) * 8]);
                    z = __builtin_amdgcn_mfma_f32_16x16x32_bf16(qf[mt2][kt], kf, z, 0, 0, 0);
                }
                for (int r = 0; r < 4; r++) {
                    float p = EXP2(z[r] + bv[nt]);
                    psum[mt2][r] += p;
                    Ps[wid][(mt2 * 16 + qd * 4 + r) * 72 + nt * 16 + c] = f2bf_fast(p);
                }
            }
        }
        for (int mt2 = 0; mt2 < 2; mt2++) {
            shortx8 pf[2];
            for (int kt = 0; kt < 2; kt++)
                pf[kt] = *(shortx8*)(&Ps[wid][(mt2 * 16 + c) * 72 + kt * 32 + qd * 8]);
            for (int nt = 0; nt < 4; nt++)
                for (int kt = 0; kt < 2; kt++) {
                    shortx8 vf = *(shortx8*)(&Vs[(nt * 16 + c) * 64 + ((kt * 4 + qd) ^ swz8) * 8]);
                    o[mt2][nt] = __builtin_amdgcn_mfma_f32_16x16x32_bf16(pf[kt], vf, o[mt2][nt], 0, 0, 0);
                }
        }
        __syncthreads();
    }

    for (int mt2 = 0; mt2 < 2; mt2++)
        for (int r = 0; r < 4; r++) {
            float l = psum[mt2][r];
            for (int off = 1; off < 16; off <<= 1)
                l += __shfl_xor(l, off, 64);
            float inv = 1.0f / l;
            size_t rowbase = ((size_t)b * L1D + q0 + wid * 32 + mt2 * 16 + qd * 4 + r) * HD + h * 64;
            for (int nt = 0; nt < 4; nt++)
                out[rowbase + nt * 16 + c] = o[mt2][nt][r] * inv;
        }
}

// ---------------------------------------------------------------------------
extern "C" void kernel_launch(void* const* d_in, const int* in_sizes, int n_in,
                              void* d_out, int out_size, void* d_ws, size_t ws_size,
                              hipStream_t stream) {
    const float* x  = (const float*)d_in[0];
    const float* y  = (const float*)d_in[1];
    const int*  ym  = (const int*)d_in[2];
    const float* Wq = (const float*)d_in[3];
    const float* bq = (const float*)d_in[4];
    const float* Wk = (const float*)d_in[5];
    const float* bk = (const float*)d_in[6];
    const float* Wv = (const float*)d_in[7];
    const float* bv = (const float*)d_in[8];
    float* outp = (float*)d_out;

    const size_t M = (size_t)BATCH * L1D;      // 16384
    const size_t T = M * HD;                   // 16.78M
    unsigned short* Obuf = (unsigned short*)d_ws;     // M*3072 (QKV fused)
    unsigned short* xb   = Obuf + M * OHD;            // T ; reused as Vt after gemm
    unsigned short* yb   = xb + T;                    // T
    unsigned short* Wt   = yb + T;                    // 3072*1024
    float* biasf         = (float*)(Wt + (size_t)OHD * DIN);
    // total ~174 MB

    const float QSCALE = 0.125f * 1.44269504088896340736f;  // 1/sqrt(64)*log2(e)

    prep_kernel<<<2 * NCVT + (BATCH * L2D) / 256, 256, 0, stream>>>(x, y, xb, yb, ym, biasf);
    wt_kernel<<<dim3(HD / 32, DIN / 32, 3), dim3(32, 8), 0, stream>>>(Wq, Wk, Wv, Wt);
    gemm_kernel<<<dim3(OHD / 256, M / 256), 512, 0, stream>>>(xb, yb, Wt, bq, bk, bv, Obuf, QSCALE);
    vt_kernel<<<dim3(L2D / 64, BATCH * NH), 256, 0, stream>>>(Obuf + 2 * HD, xb);
    attn_kernel<<<dim3(L1D / 128, BATCH * NH), 256, 0, stream>>>(Obuf, xb, biasf, outp);
}